// Round 13
// baseline (160.327 us; speedup 1.0000x reference)
//
#include <hip/hip_runtime.h>
#include <stdint.h>

#define DD 128                 // drug feature dim
#define HH 32                  // hidden dim
#define RS32 20                // h-row stride in b32 (80 B): 16B-aligned b128, <=2-way banks
#define TABQ (4096 * DD / 4)   // float4 count of drug table
#define BLOB_OFF (1u << 20)    // weight fragment blob offset inside d_ws (bytes)

typedef _Float16 f16;
typedef _Float16 f16x2 __attribute__((ext_vector_type(2)));
typedef _Float16 f16x4 __attribute__((ext_vector_type(4)));
typedef _Float16 f16x8 __attribute__((ext_vector_type(8)));
typedef float    f32x4 __attribute__((ext_vector_type(4)));

// k-permutation for layers 2-4: h is stored packed (f16x2 per b32: lo=cols 0-15,
// hi=cols 16-31), so physical f16 slot p in a row maps to logical column
// kappa(p) = (p&1) ? 16 + (p>>1) : (p>>1). B-fragments of W2/W3/W4 are
// pre-swizzled with the same permutation so A and B agree on k-order.

// Pre-pass: (a) drug table f32->f16 (blocks 0..511); (b) weight-fragment blob
// at ws+1MB (block 512): W1 slots 0..511 (natural k-order), W2 512..639,
// W3 640..767 (kappa-permuted), W4-column 768..831 (kappa-permuted, m==0 col).
__global__ __launch_bounds__(256)
void synergy_prepass(const float* __restrict__ drug,
                     const float* __restrict__ W1, const float* __restrict__ W2,
                     const float* __restrict__ W3, const float* __restrict__ W4,
                     f16* __restrict__ tab)
{
    const int tid = threadIdx.x;
    if ((int)blockIdx.x == 512) {
        f16x8* __restrict__ blob16 = (f16x8*)((char*)tab + BLOB_OFF);
        const float4* __restrict__ W1v = (const float4*)W1;
        #pragma unroll
        for (int p = 0; p < 2; ++p) {            // W1: natural k-order
            const int S = p * 256 + tid;
            const int t = S >> 8, f = (S >> 6) & 3, l = S & 63;
            const int mm = l & 15, qq = l >> 4;
            const int c4 = (t * 16 + mm) * (DD / 4) + f * 8 + qq * 2;
            const float4 w0 = W1v[c4], w1 = W1v[c4 + 1];
            f16x8 r;
            r[0]=(f16)w0.x; r[1]=(f16)w0.y; r[2]=(f16)w0.z; r[3]=(f16)w0.w;
            r[4]=(f16)w1.x; r[5]=(f16)w1.y; r[6]=(f16)w1.z; r[7]=(f16)w1.w;
            blob16[S] = r;
        }
        {                                        // W2 / W3: kappa-permuted
            const int B = tid & 127;
            const int t = B >> 6, l = B & 63;
            const int mm = l & 15, qq = l >> 4;
            const float* __restrict__ src = (tid < 128) ? W2 : W3;
            const int n = t * 16 + mm;
            f16x8 r;
            #pragma unroll
            for (int j = 0; j < 8; ++j) {
                const int kk = ((j & 1) ? 16 : 0) + 4 * qq + (j >> 1);
                r[j] = (f16)src[n * HH + kk];
            }
            blob16[512 + (tid & 128) + B] = r;
        }
        if (tid < 64) {                          // W4 column, kappa-permuted
            const int mm = tid & 15, qq = tid >> 4;
            f16x8 r;
            #pragma unroll
            for (int j = 0; j < 8; ++j) {
                const int kk = ((j & 1) ? 16 : 0) + 4 * qq + (j >> 1);
                r[j] = (mm == 0) ? (f16)W4[kk] : (f16)0.0f;
            }
            blob16[768 + tid] = r;
        }
        return;
    }
    const int i = blockIdx.x * 256 + tid;
    if (i < TABQ) {
        const float4 v = ((const float4*)drug)[i];
        f16x4 h;
        h[0]=(f16)v.x; h[1]=(f16)v.y; h[2]=(f16)v.z; h[3]=(f16)v.w;
        ((f16x4*)tab)[i] = h;
    }
}

// Main: STAGE-FREE. Gather loads deliver MFMA A-fragments directly:
// f-step f, lane (q,m) loads row ed[m], bytes 64f+16q -> lanes {l,l+16,l+32,
// l+48} share one aligned 64B line (TA merge), register = A-operand after the
// triple product. No LDS park, no transpose reads, no shuffles (edge indices
// loaded broadcast per-lane). Only LDS: packed h-rows between layers (4
// ds_write_b32 + 1 ds_read_b128 per layer). 16 waves/CU (VGPR<=128, LDS 5KB).
__global__ __launch_bounds__(256, 4)
void synergy_main(const f16* __restrict__ tab, const int* __restrict__ edges,
                  const float* __restrict__ b1, const float* __restrict__ b2,
                  const float* __restrict__ b3, const float* __restrict__ b4,
                  float* __restrict__ out, int E, int NG)
{
    __shared__ __align__(16) f16x2 hbuf[4][16 * RS32];   // 5120 B total

    const int tid  = threadIdx.x;
    const int wave = tid >> 6;
    const int lane = tid & 63;
    const int m    = lane & 15;
    const int q    = lane >> 4;

    const int WSTR = (int)gridDim.x * 4;
    int g = (int)blockIdx.x * 4 + wave;
    if (g >= NG) return;

    const char* __restrict__ tabB   = (const char*)tab;
    const int4* __restrict__ edges4 = (const int4*)edges;

    // ---- per-wave constants: weights (pre-swizzled blob, L2 broadcast), biases
    const f16x8* __restrict__ blobG = (const f16x8*)(tabB + BLOB_OFF);
    f16x8 wa[2][4];
    #pragma unroll
    for (int t = 0; t < 2; ++t)
        #pragma unroll
        for (int f = 0; f < 4; ++f)
            wa[t][f] = blobG[(t * 4 + f) * 64 + lane];
    const f16x8 w2a = blobG[512 + lane], w2b = blobG[576 + lane];
    const f16x8 w3a = blobG[640 + lane], w3b = blobG[704 + lane];
    const f16x8 wf4 = blobG[768 + lane];
    const float b1a = b1[m], b1b = b1[16 + m];
    const float b2a = b2[m], b2b = b2[16 + m];
    const float b3a = b3[m], b3b = b3[16 + m];
    const float b4v = b4[0];

    f16x2* __restrict__ hb = hbuf[wave];

    // Edge indices: every lane loads the int4 of edge g*16+m (16 distinct
    // addresses, quad-replicated -> broadcast-friendly).
    auto load_ed = [&](int gg) -> int4 {
        int e = (gg << 4) + m;
        e = (e < E) ? e : (E - 1);
        return edges4[e];
    };
    // Direct A-fragment gather: dat[f*3+t] = 16B of row ed.{x,y,z} at 64f+16q.
    f16x8 dat[12];
    auto issue_loads = [&](const int4 ed) {
        const int qo = q << 4;
        const size_t rx = (size_t)ed.x << 8;
        const size_t ry = (size_t)ed.y << 8;
        const size_t rz = (size_t)ed.z << 8;
        #pragma unroll
        for (int f = 0; f < 4; ++f) {
            dat[f * 3 + 0] = *(const f16x8*)(tabB + rx + f * 64 + qo);
            dat[f * 3 + 1] = *(const f16x8*)(tabB + ry + f * 64 + qo);
            dat[f * 3 + 2] = *(const f16x8*)(tabB + rz + f * 64 + qo);
        }
    };

    // ---- prologue
    int4 ed0 = load_ed(g);
    issue_loads(ed0);
    float lbl = (float)ed0.w;
    int gn = g + WSTR;
    int4 ed1 = load_ed((gn < NG) ? gn : g);

    for (;;) {
        // ---- Phase A: L1 (8 MFMAs, K=128); consumes dat directly
        f32x4 acc0 = {b1a, b1a, b1a, b1a};
        f32x4 acc1 = {b1b, b1b, b1b, b1b};
        #pragma unroll
        for (int f = 0; f < 4; ++f) {
            const f16x8 p = dat[f * 3 + 0] * dat[f * 3 + 1] * dat[f * 3 + 2];
            acc0 = __builtin_amdgcn_mfma_f32_16x16x32_f16(p, wa[0][f], acc0, 0, 0, 0);
            acc1 = __builtin_amdgcn_mfma_f32_16x16x32_f16(p, wa[1][f], acc1, 0, 0, 0);
        }

        // ---- issue next group's gathers (dat regs free; B-D cover the flight)
        const float lblN = (float)ed1.w;
        if (gn < NG) issue_loads(ed1);
        const int gf = gn + WSTR;
        const int4 ed2 = load_ed((gf < NG) ? gf : g);

        // h1 -> packed LDS rows
        #pragma unroll
        for (int r = 0; r < 4; ++r) {
            f16x2 v;
            v[0] = (f16)fmaxf(acc0[r], 0.0f);
            v[1] = (f16)fmaxf(acc1[r], 0.0f);
            hb[(4 * q + r) * RS32 + m] = v;
        }

        // ---- Phase B: L2 (A-operand: packed row m, phys slots 8q..8q+7)
        {
            const f16x8 a2 = *(const f16x8*)&hb[m * RS32 + q * 4];
            f32x4 c0 = {b2a, b2a, b2a, b2a};
            f32x4 c1 = {b2b, b2b, b2b, b2b};
            c0 = __builtin_amdgcn_mfma_f32_16x16x32_f16(a2, w2a, c0, 0, 0, 0);
            c1 = __builtin_amdgcn_mfma_f32_16x16x32_f16(a2, w2b, c1, 0, 0, 0);
            #pragma unroll
            for (int r = 0; r < 4; ++r) {
                f16x2 v;
                v[0] = (f16)fmaxf(c0[r], 0.0f);
                v[1] = (f16)fmaxf(c1[r], 0.0f);
                hb[(4 * q + r) * RS32 + m] = v;
            }
        }

        // ---- Phase C: L3
        {
            const f16x8 a3 = *(const f16x8*)&hb[m * RS32 + q * 4];
            f32x4 d0 = {b3a, b3a, b3a, b3a};
            f32x4 d1 = {b3b, b3b, b3b, b3b};
            d0 = __builtin_amdgcn_mfma_f32_16x16x32_f16(a3, w3a, d0, 0, 0, 0);
            d1 = __builtin_amdgcn_mfma_f32_16x16x32_f16(a3, w3b, d1, 0, 0, 0);
            #pragma unroll
            for (int r = 0; r < 4; ++r) {
                f16x2 v;
                v[0] = (f16)fmaxf(d0[r], 0.0f);
                v[1] = (f16)fmaxf(d1[r], 0.0f);
                hb[(4 * q + r) * RS32 + m] = v;
            }
        }

        // ---- Phase D: L4 as MFMA vs kappa-permuted W4 column; col 0 = result
        {
            const f16x8 a4 = *(const f16x8*)&hb[m * RS32 + q * 4];
            f32x4 z = {b4v, b4v, b4v, b4v};
            z = __builtin_amdgcn_mfma_f32_16x16x32_f16(a4, wf4, z, 0, 0, 0);
            if (m == 0) {                        // lanes 0,16,32,48: rows 4q..4q+3
                const int e0 = (g << 4) + 4 * q;
                float4 res;
                res.x = 1.0f / (1.0f + __expf(-z[0]));
                res.y = 1.0f / (1.0f + __expf(-z[1]));
                res.z = 1.0f / (1.0f + __expf(-z[2]));
                res.w = 1.0f / (1.0f + __expf(-z[3]));
                if (e0 + 3 < E) *(float4*)(out + e0) = res;
                else {
                    if (e0 + 0 < E) out[e0 + 0] = res.x;
                    if (e0 + 1 < E) out[e0 + 1] = res.y;
                    if (e0 + 2 < E) out[e0 + 2] = res.z;
                }
            }
        }
        // label pass-through (lane<16 has m==lane)
        const int eL = (g << 4) + lane;
        if (lane < 16 && eL < E) out[E + eL] = lbl;

        if (gn >= NG) break;
        g = gn; gn = gf; lbl = lblN; ed1 = ed2;
    }
}

extern "C" void kernel_launch(void* const* d_in, const int* in_sizes, int n_in,
                              void* d_out, int out_size, void* d_ws, size_t ws_size,
                              hipStream_t stream)
{
    const float* drug  = (const float*)d_in[0];
    // d_in[1] (cell_hidden_out), d_in[3] (proj_W), d_in[4] (proj_b): dead code
    const int*   edges = (const int*)d_in[2];
    const float* W1 = (const float*)d_in[5];
    const float* b1 = (const float*)d_in[6];
    const float* W2 = (const float*)d_in[7];
    const float* b2 = (const float*)d_in[8];
    const float* W3 = (const float*)d_in[9];
    const float* b3 = (const float*)d_in[10];
    const float* W4 = (const float*)d_in[11];
    const float* b4 = (const float*)d_in[12];
    float* out = (float*)d_out;
    f16*   tab = (f16*)d_ws;   // [0,1MB): f16 table; [1MB,+13KB): weight blob

    const int E  = in_sizes[2] / 4;
    const int NG = (E + 15) / 16;

    hipLaunchKernelGGL(synergy_prepass, dim3(513), dim3(256), 0, stream,
                       drug, W1, W2, W3, W4, tab);
    int blocks = (NG + 3) / 4;
    if (blocks > 1024) blocks = 1024;        // 4 blocks/CU x 256 CUs
    hipLaunchKernelGGL(synergy_main, dim3(blocks), dim3(256), 0, stream,
                       tab, edges, b1, b2, b3, b4, out, E, NG);
}

// Round 14
// 124.048 us; speedup vs baseline: 1.2925x; 1.2925x over previous
//
#include <hip/hip_runtime.h>
#include <stdint.h>

#define DD 128                 // drug feature dim
#define HH 32                  // hidden dim
#define RS 36                  // f16 per h-row (72 B): 18m mod 32 all-distinct -> conflict-free
#define TABQ (4096 * DD / 4)   // float4 count of drug table
#define BLOB_OFF (1u << 20)    // weight fragment blob offset inside d_ws (bytes)

typedef _Float16 f16;
typedef _Float16 f16x4 __attribute__((ext_vector_type(4)));
typedef _Float16 f16x8 __attribute__((ext_vector_type(8)));
typedef float    f32x4 __attribute__((ext_vector_type(4)));

#define GL1(p)  ((const __attribute__((address_space(1))) void*)(p))
#define LDS3(p) ((__attribute__((address_space(3))) void*)(p))

// Pre-pass: (a) drug table f32->f16 (blocks 0..511); (b) weight-fragment blob
// at ws+1MB (block 512): W1 slots 0..511, W2 512..639, W3 640..767,
// W4-column-fragment 768..831 (lane m==0 holds W4[8q+j], else 0).
__global__ __launch_bounds__(256)
void synergy_prepass(const float* __restrict__ drug,
                     const float* __restrict__ W1, const float* __restrict__ W2,
                     const float* __restrict__ W3, const float* __restrict__ W4,
                     f16* __restrict__ tab)
{
    const int tid = threadIdx.x;
    if ((int)blockIdx.x == 512) {
        f16x8* __restrict__ blob16 = (f16x8*)((char*)tab + BLOB_OFF);
        const float4* __restrict__ W1v = (const float4*)W1;
        #pragma unroll
        for (int p = 0; p < 2; ++p) {
            const int S = p * 256 + tid;
            const int t = S >> 8, f = (S >> 6) & 3, l = S & 63;
            const int mm = l & 15, qq = l >> 4;
            const int c4 = (t * 16 + mm) * (DD / 4) + f * 8 + qq * 2;
            const float4 w0 = W1v[c4], w1 = W1v[c4 + 1];
            f16x8 r;
            r[0]=(f16)w0.x; r[1]=(f16)w0.y; r[2]=(f16)w0.z; r[3]=(f16)w0.w;
            r[4]=(f16)w1.x; r[5]=(f16)w1.y; r[6]=(f16)w1.z; r[7]=(f16)w1.w;
            blob16[S] = r;
        }
        {
            const int B = tid & 127;
            const int t = B >> 6, l = B & 63;
            const int mm = l & 15, qq = l >> 4;
            const int c4 = (t * 16 + mm) * (HH / 4) + qq * 2;
            const float4* __restrict__ src = (tid < 128) ? (const float4*)W2 : (const float4*)W3;
            const float4 w0 = src[c4], w1 = src[c4 + 1];
            f16x8 r;
            r[0]=(f16)w0.x; r[1]=(f16)w0.y; r[2]=(f16)w0.z; r[3]=(f16)w0.w;
            r[4]=(f16)w1.x; r[5]=(f16)w1.y; r[6]=(f16)w1.z; r[7]=(f16)w1.w;
            blob16[512 + (tid & 128) + B] = r;
        }
        if (tid < 64) {                         // W4 column fragment
            const int mm = tid & 15, qq = tid >> 4;
            f16x8 r;
            #pragma unroll
            for (int j = 0; j < 8; ++j)
                r[j] = (mm == 0) ? (f16)W4[qq * 8 + j] : (f16)0.0f;
            blob16[768 + tid] = r;
        }
        return;
    }
    const int i = blockIdx.x * 256 + tid;
    if (i < TABQ) {
        const float4 v = ((const float4*)drug)[i];
        f16x4 h;
        h[0]=(f16)v.x; h[1]=(f16)v.y; h[2]=(f16)v.z; h[3]=(f16)v.w;
        ((f16x4*)tab)[i] = h;
    }
}

// Main: PERSISTENT, TAIL-ISSUE pipeline (best-known configuration, r9).
// Per iteration: loop-top vmcnt(0) (sole drain point) -> phases A-D (all LDS
// traffic here) -> stores -> edge shuffles -> issue next group's 12 DMAs LAST.
// DMA flight covered by 12 resident waves/CU. L4 via zero-padded W4 column
// fragment MFMA. Measured: ~44 us main kernel = ~92% of the scattered-address
// service floor (24M 16B lane-addrs at ~1 addr/cy/CU = 39.2 us).
__global__ __launch_bounds__(256, 3)
void synergy_main(const f16* __restrict__ tab, const int* __restrict__ edges,
                  const float* __restrict__ b1, const float* __restrict__ b2,
                  const float* __restrict__ b3, const float* __restrict__ b4,
                  float* __restrict__ out, int E, int NG)
{
    __shared__ __align__(16) f16 stage[4][6144];   // 48 KiB: 48 rows x 256 B per wave
    __shared__ __align__(16) f16 hbuf[4][16 * RS]; // 4.5 KiB per block

    const int tid  = threadIdx.x;
    const int wave = tid >> 6;
    const int lane = tid & 63;
    const int m    = lane & 15;
    const int q    = lane >> 4;

    const int WSTR = (int)gridDim.x * 4;
    int g = (int)blockIdx.x * 4 + wave;
    if (g >= NG) return;

    const char* __restrict__ tabB   = (const char*)tab;
    const int4* __restrict__ edges4 = (const int4*)edges;

    // ---- per-wave constants: weights (pre-swizzled blob, L2 broadcast), biases
    const f16x8* __restrict__ blobG = (const f16x8*)(tabB + BLOB_OFF);
    f16x8 wa[2][4];
    #pragma unroll
    for (int t = 0; t < 2; ++t)
        #pragma unroll
        for (int f = 0; f < 4; ++f)
            wa[t][f] = blobG[(t * 4 + f) * 64 + lane];
    const f16x8 w2a = blobG[512 + lane], w2b = blobG[576 + lane];
    const f16x8 w3a = blobG[640 + lane], w3b = blobG[704 + lane];
    const f16x8 wf4 = blobG[768 + lane];
    const float b1a = b1[m], b1b = b1[16 + m];
    const float b2a = b2[m], b2b = b2[16 + m];
    const float b3a = b3[m], b3b = b3[16 + m];
    const float b4v = b4[0];

    f16* __restrict__ stg = stage[wave];
    f16* __restrict__ hb  = hbuf[wave];

    auto load_ed = [&](int gg) -> int4 {
        int e = (gg << 4) + m;
        e = (e < E) ? e : (E - 1);
        return edges4[e];
    };
    // Rotation-swizzled gather: DMA (t,gg) -> lane 16q+m stages row 4gg+q,
    // slot m, fetching global segment (m + 4gg + q) & 15 of that row.
    auto issue_dma = [&](const int4 ed) {
        int rowb[12];
        #pragma unroll
        for (int gg = 0; gg < 4; ++gg) {
            const int src = 4 * gg + q;
            rowb[0 * 4 + gg] = __shfl(ed.x, src, 64) << 8;
            rowb[1 * 4 + gg] = __shfl(ed.y, src, 64) << 8;
            rowb[2 * 4 + gg] = __shfl(ed.z, src, 64) << 8;
        }
        __builtin_amdgcn_sched_barrier(0);
        #pragma unroll
        for (int t = 0; t < 3; ++t)
            #pragma unroll
            for (int gg = 0; gg < 4; ++gg) {
                const int seg16 = ((m + 4 * gg + q) & 15) << 4;
                __builtin_amdgcn_global_load_lds(
                    GL1(tabB + (size_t)(rowb[t * 4 + gg] + seg16)),
                    LDS3((char*)stg + (t * 16 + 4 * gg) * 256), 16, 0, 0);
            }
    };

    // ---- prologue
    int4 ed_cur = load_ed(g);
    issue_dma(ed_cur);
    int gn = g + WSTR;
    int4 ed_nxt = load_ed((gn < NG) ? gn : g);

    for (;;) {
        __builtin_amdgcn_s_waitcnt(0x0F70);     // vmcnt(0): stage DMAs landed
        __builtin_amdgcn_sched_barrier(0);

        // ---- Phase A: L1 (8 MFMAs, K=128); consumes stage
        f32x4 acc0 = {b1a, b1a, b1a, b1a};
        f32x4 acc1 = {b1b, b1b, b1b, b1b};
        #pragma unroll
        for (int f = 0; f < 4; ++f) {
            const int slot = (((f * 4 + q) - m) & 15) << 3;
            const f16x8 v0 = *(const f16x8*)(stg + (0 * 16 + m) * 128 + slot);
            const f16x8 v1 = *(const f16x8*)(stg + (1 * 16 + m) * 128 + slot);
            const f16x8 v2 = *(const f16x8*)(stg + (2 * 16 + m) * 128 + slot);
            const f16x8 p = v0 * v1 * v2;
            acc0 = __builtin_amdgcn_mfma_f32_16x16x32_f16(p, wa[0][f], acc0, 0, 0, 0);
            acc1 = __builtin_amdgcn_mfma_f32_16x16x32_f16(p, wa[1][f], acc1, 0, 0, 0);
        }
        #pragma unroll
        for (int r = 0; r < 4; ++r) {
            const int row = 4 * q + r;
            hb[row * RS + m]      = (f16)fmaxf(acc0[r], 0.0f);
            hb[row * RS + 16 + m] = (f16)fmaxf(acc1[r], 0.0f);
        }

        // ---- prefetch edges two groups ahead (register; drained next top-wait)
        const int gf = gn + WSTR;
        const int4 ed_fut = load_ed((gf < NG) ? gf : g);

        // ---- Phase B: L2
        {
            const f16x8 a2 = *(const f16x8*)(hb + m * RS + q * 8);
            f32x4 c0 = {b2a, b2a, b2a, b2a};
            f32x4 c1 = {b2b, b2b, b2b, b2b};
            c0 = __builtin_amdgcn_mfma_f32_16x16x32_f16(a2, w2a, c0, 0, 0, 0);
            c1 = __builtin_amdgcn_mfma_f32_16x16x32_f16(a2, w2b, c1, 0, 0, 0);
            #pragma unroll
            for (int r = 0; r < 4; ++r) {
                const int row = 4 * q + r;
                hb[row * RS + m]      = (f16)fmaxf(c0[r], 0.0f);
                hb[row * RS + 16 + m] = (f16)fmaxf(c1[r], 0.0f);
            }
        }

        // ---- Phase C: L3 (h3 back to LDS for L4's A-operand)
        {
            const f16x8 a3 = *(const f16x8*)(hb + m * RS + q * 8);
            f32x4 d0 = {b3a, b3a, b3a, b3a};
            f32x4 d1 = {b3b, b3b, b3b, b3b};
            d0 = __builtin_amdgcn_mfma_f32_16x16x32_f16(a3, w3a, d0, 0, 0, 0);
            d1 = __builtin_amdgcn_mfma_f32_16x16x32_f16(a3, w3b, d1, 0, 0, 0);
            #pragma unroll
            for (int r = 0; r < 4; ++r) {
                const int row = 4 * q + r;
                hb[row * RS + m]      = (f16)fmaxf(d0[r], 0.0f);
                hb[row * RS + 16 + m] = (f16)fmaxf(d1[r], 0.0f);
            }
        }

        // ---- Phase D: L4 as MFMA vs zero-padded W4 column; col 0 = result
        {
            const f16x8 a4 = *(const f16x8*)(hb + m * RS + q * 8);
            f32x4 z = {b4v, b4v, b4v, b4v};
            z = __builtin_amdgcn_mfma_f32_16x16x32_f16(a4, wf4, z, 0, 0, 0);
            if (m == 0) {                        // lanes 0,16,32,48: rows 4q..4q+3
                const int e0 = (g << 4) + 4 * q;
                float4 res;
                res.x = 1.0f / (1.0f + __expf(-z[0]));
                res.y = 1.0f / (1.0f + __expf(-z[1]));
                res.z = 1.0f / (1.0f + __expf(-z[2]));
                res.w = 1.0f / (1.0f + __expf(-z[3]));
                if (e0 + 3 < E) *(float4*)(out + e0) = res;
                else {
                    if (e0 + 0 < E) out[e0 + 0] = res.x;
                    if (e0 + 1 < E) out[e0 + 1] = res.y;
                    if (e0 + 2 < E) out[e0 + 2] = res.z;
                }
            }
        }
        // label pass-through
        const int eL = (g << 4) + lane;
        if (lane < 16 && eL < E) out[E + eL] = (float)ed_cur.w;

        // ---- TAIL: issue next group's DMAs (nothing after this reads LDS)
        if (gn >= NG) break;
        issue_dma(ed_nxt);
        g = gn; gn = gf; ed_cur = ed_nxt; ed_nxt = ed_fut;
    }
}

extern "C" void kernel_launch(void* const* d_in, const int* in_sizes, int n_in,
                              void* d_out, int out_size, void* d_ws, size_t ws_size,
                              hipStream_t stream)
{
    const float* drug  = (const float*)d_in[0];
    // d_in[1] (cell_hidden_out), d_in[3] (proj_W), d_in[4] (proj_b): dead code
    const int*   edges = (const int*)d_in[2];
    const float* W1 = (const float*)d_in[5];
    const float* b1 = (const float*)d_in[6];
    const float* W2 = (const float*)d_in[7];
    const float* b2 = (const float*)d_in[8];
    const float* W3 = (const float*)d_in[9];
    const float* b3 = (const float*)d_in[10];
    const float* W4 = (const float*)d_in[11];
    const float* b4 = (const float*)d_in[12];
    float* out = (float*)d_out;
    f16*   tab = (f16*)d_ws;   // [0,1MB): f16 table; [1MB,+13KB): weight blob

    const int E  = in_sizes[2] / 4;
    const int NG = (E + 15) / 16;

    hipLaunchKernelGGL(synergy_prepass, dim3(513), dim3(256), 0, stream,
                       drug, W1, W2, W3, W4, tab);
    int blocks = (NG + 3) / 4;
    if (blocks > 768) blocks = 768;          // 3 blocks/CU x 256 CUs
    hipLaunchKernelGGL(synergy_main, dim3(blocks), dim3(256), 0, stream,
                       tab, edges, b1, b2, b3, b4, out, E, NG);
}